// Round 1
// baseline (1792.370 us; speedup 1.0000x reference)
//
#include <hip/hip_runtime.h>
#include <hip/hip_bf16.h>

typedef _Float16 half8 __attribute__((ext_vector_type(8)));
typedef float floatx4 __attribute__((ext_vector_type(4)));
typedef float floatx2 __attribute__((ext_vector_type(2)));

#define N_NODES 10000
#define F_NODE  128
#define C_GCN   64
#define N_EDGES 160000
#define T_SEQ   96
#define S_SEQ   32
#define HID     128
#define M_BLK   40          // nodes per block (250 blocks exactly)
#define MT      3           // 3 m-tiles of 16 -> 48 rows (40 real + 8 zero pad)
#define SEQ_STRIDE 104      // 96 + 8 f16 pad (208 B = 13*16)
#define H_STRIDE   136      // 128 + 8 f16 pad (272 B = 17*16)
#define WAVE_STREAM 61440   // bytes of packed weights per wave per step (15 slots x 4 KB)

// ---------------- fast activations: native v_exp_f32 + v_rcp_f32 ----------------
__device__ __forceinline__ float fast_rcp(float x) { return __builtin_amdgcn_rcpf(x); }
__device__ __forceinline__ float sigm_f(float x) {
    return fast_rcp(1.0f + __expf(-x));            // __expf -> v_exp_f32 (native)
}
__device__ __forceinline__ float tanh_f(float x) {
    return 2.0f * fast_rcp(1.0f + __expf(-2.0f * x)) - 1.0f;
}

// ---------------- GCN kernels (all fp32, tiny) ----------------
__global__ void k_gcn_xw(const float* __restrict__ nf, const float* __restrict__ w,
                         float* __restrict__ xw) {
    int tid = blockIdx.x * 256 + threadIdx.x;
    int n = tid >> 6, c = tid & 63;
    if (n >= N_NODES) return;
    float s = 0.f;
    #pragma unroll 8
    for (int k = 0; k < F_NODE; ++k) s = fmaf(nf[n * F_NODE + k], w[k * C_GCN + c], s);
    xw[n * C_GCN + c] = s;
}

__global__ void k_deg_init(float* __restrict__ deg) {
    int i = blockIdx.x * 256 + threadIdx.x;
    if (i < N_NODES) deg[i] = 1.0f;   // self loop
}

__global__ void k_deg_count(const int* __restrict__ ei, float* __restrict__ deg) {
    int e = blockIdx.x * 256 + threadIdx.x;
    if (e < N_EDGES) atomicAdd(&deg[ei[N_EDGES + e]], 1.0f);
}

__global__ void k_dinv(const float* __restrict__ deg, float* __restrict__ dinv) {
    int i = blockIdx.x * 256 + threadIdx.x;
    if (i < N_NODES) dinv[i] = rsqrtf(deg[i]);
}

__global__ void k_gcn_self(const float* __restrict__ xw, const float* __restrict__ dinv,
                           const float* __restrict__ gb, float* __restrict__ gout) {
    int tid = blockIdx.x * 256 + threadIdx.x;
    int n = tid >> 6, c = tid & 63;
    if (n >= N_NODES) return;
    float di = dinv[n];
    gout[tid] = xw[tid] * di * di + gb[c];
}

__global__ void k_gcn_scatter(const int* __restrict__ ei, const float* __restrict__ xw,
                              const float* __restrict__ dinv, float* __restrict__ gout) {
    int e = blockIdx.x * 4 + (threadIdx.x >> 6);
    int c = threadIdx.x & 63;
    if (e >= N_EDGES) return;
    int r  = ei[e];
    int cl = ei[N_EDGES + e];
    float nm = dinv[r] * dinv[cl];
    atomicAdd(&gout[cl * C_GCN + c], xw[r * C_GCN + c] * nm);
}

// ---------------- weight packing: wave-major streaming order ----------------
// pP layout: [wave w:8][slot s:15][gate g:4][lane:64] x half8 (16 B).
// Per wave per step: 15 contiguous 4-KB slots in exact consumption order:
//   s=0..2 IH0(kt=s,K=96), 3..6 HH0(kt=s-3), 7..10 IH1(kt=s-7), 11..14 HH1(kt=s-11)
// lane holds W[g*128 + w*16 + (lane&15)][kt*32 + (lane>>4)*8 + j]
__global__ void k_pack(const float* __restrict__ w_ih0, const float* __restrict__ w_hh0,
                       const float* __restrict__ w_ih1, const float* __restrict__ w_hh1,
                       half8* __restrict__ pP) {
    int tid = blockIdx.x * 256 + threadIdx.x;
    if (tid >= 8 * 15 * 4 * 64) return;
    int lane = tid & 63;
    int g    = (tid >> 6) & 3;
    int s    = (tid >> 8) % 15;
    int w    = tid / 3840;
    const float* src; int kt, K;
    if (s < 3)       { src = w_ih0; kt = s;      K = 96;  }
    else if (s < 7)  { src = w_hh0; kt = s - 3;  K = 128; }
    else if (s < 11) { src = w_ih1; kt = s - 7;  K = 128; }
    else             { src = w_hh1; kt = s - 11; K = 128; }
    int row = g * 128 + w * 16 + (lane & 15);
    int k0  = kt * 32 + (lane >> 4) * 8;
    half8 v;
    #pragma unroll
    for (int j = 0; j < 8; ++j) v[j] = (_Float16)src[row * K + k0 + j];
    pP[tid] = v;
}

__global__ void k_bsum(const float* __restrict__ bi0, const float* __restrict__ bh0,
                       const float* __restrict__ bi1, const float* __restrict__ bh1,
                       float* __restrict__ bs) {
    int i = blockIdx.x * 256 + threadIdx.x;
    if (i < 512)       bs[i] = bi0[i] + bh0[i];
    else if (i < 1024) bs[i] = bi1[i - 512] + bh1[i - 512];
}

// ---------------- fused 2-layer LSTM + FC ----------------
// B-operand (weights) is WAVE-PRIVATE: each wave is the sole consumer of its
// 60 KB stream. So: global -> registers -> MFMA directly (no LDS staging).
// 3-deep register ring; 15 slots % 3 == 0 so the rotation is timestep-invariant,
// and slots 13/14 prefetch the next step's slots 0/1 across the barrier.

__device__ __forceinline__ void epilogue(floatx4 acc[4][MT],
                                         float c[MT][4], _Float16* Hnext,
                                         int quad, int ch) {
    #pragma unroll
    for (int mt = 0; mt < MT; ++mt) {
        #pragma unroll
        for (int r = 0; r < 4; ++r) {
            float gi = acc[0][mt][r];
            float gf = acc[1][mt][r];
            float gg = acc[2][mt][r];
            float go = acc[3][mt][r];
            float cn = sigm_f(gf) * c[mt][r] + sigm_f(gi) * tanh_f(gg);
            c[mt][r] = cn;
            float h = sigm_f(go) * tanh_f(cn);
            Hnext[(mt * 16 + quad * 4 + r) * H_STRIDE + ch] = (_Float16)h;
        }
    }
}

// load one 4-KB slot (4 gate-frags, 16 B/lane each) into a register buffer
#define LOAD_SLOT(B, S) do {                                        \
    B[0] = *(const half8*)(pWw + (S) * 4096);                       \
    B[1] = *(const half8*)(pWw + (S) * 4096 + 1024);                \
    B[2] = *(const half8*)(pWw + (S) * 4096 + 2048);                \
    B[3] = *(const half8*)(pWw + (S) * 4096 + 3072);                \
} while (0)

// consume one k-tile: 3 A ds_reads + 12 MFMAs (B already in registers)
#define MFMA_KT(B, Aptr, strideA, koff) do {                        \
    half8 _a[MT];                                                   \
    _Pragma("unroll")                                               \
    for (int _mt = 0; _mt < MT; ++_mt)                              \
        _a[_mt] = *(const half8*)((Aptr) + (_mt * 16 + l15) * (strideA) + (koff) + quad * 8); \
    _Pragma("unroll")                                               \
    for (int _g = 0; _g < 4; ++_g)                                  \
        _Pragma("unroll")                                           \
        for (int _mt = 0; _mt < MT; ++_mt)                          \
            acc[_g][_mt] = __builtin_amdgcn_mfma_f32_16x16x32_f16(_a[_mt], B[_g], acc[_g][_mt], 0, 0, 0); \
} while (0)

__global__ __launch_bounds__(512, 2) void k_lstm(
    const float* __restrict__ seq, const float* __restrict__ gcn,
    const char* __restrict__ pW, const float* __restrict__ bsum,
    const float* __restrict__ fcw, const float* __restrict__ fcb,
    float* __restrict__ out) {

    __shared__ __align__(16) _Float16 sSeq[48 * SEQ_STRIDE];          //  9,984 B
    __shared__ __align__(16) _Float16 sH0[2][48 * H_STRIDE];          // 26,112 B
    __shared__ __align__(16) _Float16 sH1[2][48 * H_STRIDE];          // 26,112 B

    const int tid  = threadIdx.x;
    const int wid  = tid >> 6;
    const int lane = tid & 63;
    const int l15  = lane & 15;
    const int quad = lane >> 4;
    const int node0 = blockIdx.x * M_BLK;
    const int ch = wid * 16 + l15;

    const char* pWw = pW + wid * WAVE_STREAM + lane * 16;   // this wave+lane's stream base

    // prologue: slots 0 and 1 in flight during setup
    half8 b0[4], b1[4], b2[4];
    LOAD_SLOT(b0, 0);
    LOAD_SLOT(b1, 1);

    // zero LDS A-buffers (pad rows 40..47 stay zero forever)
    for (int i = tid; i < 48 * SEQ_STRIDE; i += 512) sSeq[i] = (_Float16)0.f;
    for (int i = tid; i < 48 * H_STRIDE; i += 512) {
        sH0[0][i] = (_Float16)0.f; sH0[1][i] = (_Float16)0.f;
        sH1[0][i] = (_Float16)0.f; sH1[1][i] = (_Float16)0.f;
    }

    float bias0[4], bias1[4];
    #pragma unroll
    for (int g = 0; g < 4; ++g) {
        bias0[g] = bsum[g * 128 + ch];
        bias1[g] = bsum[512 + g * 128 + ch];
    }

    float c0[MT][4] = {{0}}, c1[MT][4] = {{0}};

    __syncthreads();

    // stage constant gcn columns (32..95) and seq t=0 (cols 0..31)
    for (int i = tid; i < M_BLK * (C_GCN / 2); i += 512) {
        int r = i >> 5, cp = (i & 31) * 2;
        floatx2 v = *(const floatx2*)(gcn + (size_t)(node0 + r) * C_GCN + cp);
        sSeq[r * SEQ_STRIDE + S_SEQ + cp]     = (_Float16)v.x;
        sSeq[r * SEQ_STRIDE + S_SEQ + cp + 1] = (_Float16)v.y;
    }
    {
        int r = tid >> 4, cp = (tid & 15) * 2;
        if (tid < M_BLK * 16) {
            floatx2 v = *(const floatx2*)(seq + ((size_t)(node0 + r) * T_SEQ) * S_SEQ + cp);
            sSeq[r * SEQ_STRIDE + cp]     = (_Float16)v.x;
            sSeq[r * SEQ_STRIDE + cp + 1] = (_Float16)v.y;
        }
    }
    __syncthreads();

    floatx4 acc[4][MT];
    const int pr  = tid >> 4, pc = (tid & 15) * 2;           // seq prefetch slot
    const int pr2 = (512 + tid) >> 4, pc2 = ((512 + tid) & 15) * 2;

    for (int t = 0; t < T_SEQ; ++t) {
        const int cur = t & 1, nxt = cur ^ 1;
        const _Float16* h0c = &sH0[cur][0];
        _Float16*       h0n = &sH0[nxt][0];
        const _Float16* h1c = &sH1[cur][0];
        _Float16*       h1n = &sH1[nxt][0];

        // register prefetch of seq(t+1): in flight through phase A
        floatx2 pf0 = {0.f, 0.f}, pf1 = {0.f, 0.f};
        if (t + 1 < T_SEQ) {
            pf0 = *(const floatx2*)(seq + ((size_t)(node0 + pr) * T_SEQ + (t + 1)) * S_SEQ + pc);
            if (tid < 128)
                pf1 = *(const floatx2*)(seq + ((size_t)(node0 + pr2) * T_SEQ + (t + 1)) * S_SEQ + pc2);
        }

        // ---- phase A: slots 0..6 (0..2: sSeq x IH0, 3..6: sH0 x HH0) ----
        #pragma unroll
        for (int g = 0; g < 4; ++g) {
            floatx4 bv = {bias0[g], bias0[g], bias0[g], bias0[g]};
            #pragma unroll
            for (int mt = 0; mt < MT; ++mt) acc[g][mt] = bv;
        }
        LOAD_SLOT(b2, 2);  MFMA_KT(b0, sSeq, SEQ_STRIDE, 0);        // slot 0
        LOAD_SLOT(b0, 3);  MFMA_KT(b1, sSeq, SEQ_STRIDE, 32);       // slot 1
        LOAD_SLOT(b1, 4);  MFMA_KT(b2, sSeq, SEQ_STRIDE, 64);       // slot 2
        LOAD_SLOT(b2, 5);  MFMA_KT(b0, h0c, H_STRIDE, 0);           // slot 3
        LOAD_SLOT(b0, 6);  MFMA_KT(b1, h0c, H_STRIDE, 32);          // slot 4
        LOAD_SLOT(b1, 7);  MFMA_KT(b2, h0c, H_STRIDE, 64);          // slot 5
        LOAD_SLOT(b2, 8);  MFMA_KT(b0, h0c, H_STRIDE, 96);          // slot 6
        epilogue(acc, c0, h0n, quad, ch);
        __syncthreads();  // h0(t) visible for layer 1

        // ---- phase B: slots 7..14 (7..10: sH0[nxt] x IH1, 11..14: sH1 x HH1) ----
        #pragma unroll
        for (int g = 0; g < 4; ++g) {
            floatx4 bv = {bias1[g], bias1[g], bias1[g], bias1[g]};
            #pragma unroll
            for (int mt = 0; mt < MT; ++mt) acc[g][mt] = bv;
        }
        LOAD_SLOT(b0, 9);   MFMA_KT(b1, h0n, H_STRIDE, 0);          // slot 7
        LOAD_SLOT(b1, 10);  MFMA_KT(b2, h0n, H_STRIDE, 32);         // slot 8
        LOAD_SLOT(b2, 11);  MFMA_KT(b0, h0n, H_STRIDE, 64);         // slot 9
        LOAD_SLOT(b0, 12);  MFMA_KT(b1, h0n, H_STRIDE, 96);         // slot 10
        LOAD_SLOT(b1, 13);  MFMA_KT(b2, h1c, H_STRIDE, 0);          // slot 11
        LOAD_SLOT(b2, 14);  MFMA_KT(b0, h1c, H_STRIDE, 32);         // slot 12
        LOAD_SLOT(b0, 0);   MFMA_KT(b1, h1c, H_STRIDE, 64);         // slot 13: prefetch next-step slot 0
        LOAD_SLOT(b1, 1);   MFMA_KT(b2, h1c, H_STRIDE, 96);         // slot 14: prefetch next-step slot 1

        // commit seq(t+1) from prefetch regs (phase-A readers of sSeq are done)
        if (t + 1 < T_SEQ) {
            sSeq[pr * SEQ_STRIDE + pc]     = (_Float16)pf0.x;
            sSeq[pr * SEQ_STRIDE + pc + 1] = (_Float16)pf0.y;
            if (tid < 128) {
                sSeq[pr2 * SEQ_STRIDE + pc2]     = (_Float16)pf1.x;
                sSeq[pr2 * SEQ_STRIDE + pc2 + 1] = (_Float16)pf1.y;
            }
        }
        epilogue(acc, c1, h1n, quad, ch);
        __syncthreads();  // h1(t) + seq(t+1) visible
    }

    // final h1 lives in buffer (T_SEQ & 1) == 0
    if (tid < M_BLK) {
        const _Float16* h1 = &sH1[0][tid * H_STRIDE];
        float s = fcb[0];
        #pragma unroll 16
        for (int k = 0; k < HID; ++k) s = fmaf((float)h1[k], fcw[k], s);
        out[node0 + tid] = s;
    }
}

// ---------------- launch ----------------
extern "C" void kernel_launch(void* const* d_in, const int* in_sizes, int n_in,
                              void* d_out, int out_size, void* d_ws, size_t ws_size,
                              hipStream_t stream) {
    const float* seq   = (const float*)d_in[0];
    const int*   ei    = (const int*)d_in[1];     // int64 in reference -> int32 on device
    // d_in[2] edge_attr: unused by reference
    const float* nf    = (const float*)d_in[3];
    // d_in[4] node_indices: unused by reference
    const float* gcn_w = (const float*)d_in[5];
    const float* gcn_b = (const float*)d_in[6];
    const float* w_ih0 = (const float*)d_in[7];
    const float* w_hh0 = (const float*)d_in[8];
    const float* b_ih0 = (const float*)d_in[9];
    const float* b_hh0 = (const float*)d_in[10];
    const float* w_ih1 = (const float*)d_in[11];
    const float* w_hh1 = (const float*)d_in[12];
    const float* b_ih1 = (const float*)d_in[13];
    const float* b_hh1 = (const float*)d_in[14];
    const float* fc_w  = (const float*)d_in[15];
    const float* fc_b  = (const float*)d_in[16];
    float* out = (float*)d_out;

    char* ws = (char*)d_ws;
    float* xw   = (float*)(ws);                    // 2,560,000 B
    float* gout = (float*)(ws + 2621440);          // 2,560,000 B
    float* deg  = (float*)(ws + 5242880);          // 40,000 B
    float* dinv = (float*)(ws + 5283840);          // 40,000 B
    float* bsum = (float*)(ws + 5324800);          // 4,096 B
    char*  pP   = (char*)(ws + 5328896);           // 491,520 B (16B aligned)

    // GCN (fp32 exact)
    k_gcn_xw     <<<2500,  256, 0, stream>>>(nf, gcn_w, xw);
    k_deg_init   <<<40,    256, 0, stream>>>(deg);
    k_deg_count  <<<625,   256, 0, stream>>>(ei, deg);
    k_dinv       <<<40,    256, 0, stream>>>(deg, dinv);
    k_gcn_self   <<<2500,  256, 0, stream>>>(xw, dinv, gcn_b, gout);
    k_gcn_scatter<<<40000, 256, 0, stream>>>(ei, xw, dinv, gout);

    // weight prep (wave-major streaming layout)
    k_pack<<<120, 256, 0, stream>>>(w_ih0, w_hh0, w_ih1, w_hh1, (half8*)pP);
    k_bsum<<<4,   256, 0, stream>>>(b_ih0, b_hh0, b_ih1, b_hh1, bsum);

    // fused 2-layer LSTM + FC
    k_lstm<<<250, 512, 0, stream>>>(seq, gout, pP, bsum, fc_w, fc_b, out);
}

// Round 3
// 1284.454 us; speedup vs baseline: 1.3954x; 1.3954x over previous
//
#include <hip/hip_runtime.h>
#include <hip/hip_bf16.h>

typedef _Float16 half8 __attribute__((ext_vector_type(8)));
typedef float floatx4 __attribute__((ext_vector_type(4)));
typedef float floatx2 __attribute__((ext_vector_type(2)));

#define N_NODES 10000
#define F_NODE  128
#define C_GCN   64
#define N_EDGES 160000
#define T_SEQ   96
#define S_SEQ   32
#define HID     128
#define M_BLK   40          // nodes per block (250 blocks exactly)
#define MT      3           // 3 m-tiles of 16 -> 48 rows (40 real + 8 zero pad)
#define SEQ_STRIDE 104      // 96 + 8 f16 pad (208 B = 13*16)
#define H_STRIDE   136      // 128 + 8 f16 pad (272 B = 17*16)
#define WAVE_STREAM 61440   // bytes of packed weights per wave per step (15 slots x 4 KB)

// ---------------- fast activations: native v_exp_f32 + v_rcp_f32 ----------------
__device__ __forceinline__ float fast_rcp(float x) { return __builtin_amdgcn_rcpf(x); }
__device__ __forceinline__ float sigm_f(float x) {
    return fast_rcp(1.0f + __expf(-x));            // __expf -> v_exp_f32 (native)
}
__device__ __forceinline__ float tanh_f(float x) {
    return 2.0f * fast_rcp(1.0f + __expf(-2.0f * x)) - 1.0f;
}

// ---------------- GCN kernels (all fp32, tiny) ----------------
__global__ void k_gcn_xw(const float* __restrict__ nf, const float* __restrict__ w,
                         float* __restrict__ xw) {
    int tid = blockIdx.x * 256 + threadIdx.x;
    int n = tid >> 6, c = tid & 63;
    if (n >= N_NODES) return;
    float s = 0.f;
    #pragma unroll 8
    for (int k = 0; k < F_NODE; ++k) s = fmaf(nf[n * F_NODE + k], w[k * C_GCN + c], s);
    xw[n * C_GCN + c] = s;
}

__global__ void k_deg_init(float* __restrict__ deg) {
    int i = blockIdx.x * 256 + threadIdx.x;
    if (i < N_NODES) deg[i] = 1.0f;   // self loop
}

__global__ void k_deg_count(const int* __restrict__ ei, float* __restrict__ deg) {
    int e = blockIdx.x * 256 + threadIdx.x;
    if (e < N_EDGES) atomicAdd(&deg[ei[N_EDGES + e]], 1.0f);
}

__global__ void k_dinv(const float* __restrict__ deg, float* __restrict__ dinv) {
    int i = blockIdx.x * 256 + threadIdx.x;
    if (i < N_NODES) dinv[i] = rsqrtf(deg[i]);
}

__global__ void k_gcn_self(const float* __restrict__ xw, const float* __restrict__ dinv,
                           const float* __restrict__ gb, float* __restrict__ gout) {
    int tid = blockIdx.x * 256 + threadIdx.x;
    int n = tid >> 6, c = tid & 63;
    if (n >= N_NODES) return;
    float di = dinv[n];
    gout[tid] = xw[tid] * di * di + gb[c];
}

__global__ void k_gcn_scatter(const int* __restrict__ ei, const float* __restrict__ xw,
                              const float* __restrict__ dinv, float* __restrict__ gout) {
    int e = blockIdx.x * 4 + (threadIdx.x >> 6);
    int c = threadIdx.x & 63;
    if (e >= N_EDGES) return;
    int r  = ei[e];
    int cl = ei[N_EDGES + e];
    float nm = dinv[r] * dinv[cl];
    atomicAdd(&gout[cl * C_GCN + c], xw[r * C_GCN + c] * nm);
}

// ---------------- weight packing: wave-major streaming order ----------------
// pP layout: [wave w:8][slot s:15][gate g:4][lane:64] x half8 (16 B).
// Per wave per step: 15 contiguous 4-KB slots in exact consumption order:
//   s=0..2 IH0(kt=s,K=96), 3..6 HH0(kt=s-3), 7..10 IH1(kt=s-7), 11..14 HH1(kt=s-11)
// lane holds W[g*128 + w*16 + (lane&15)][kt*32 + (lane>>4)*8 + j]
__global__ void k_pack(const float* __restrict__ w_ih0, const float* __restrict__ w_hh0,
                       const float* __restrict__ w_ih1, const float* __restrict__ w_hh1,
                       half8* __restrict__ pP) {
    int tid = blockIdx.x * 256 + threadIdx.x;
    if (tid >= 8 * 15 * 4 * 64) return;
    int lane = tid & 63;
    int g    = (tid >> 6) & 3;
    int s    = (tid >> 8) % 15;
    int w    = tid / 3840;
    const float* src; int kt, K;
    if (s < 3)       { src = w_ih0; kt = s;      K = 96;  }
    else if (s < 7)  { src = w_hh0; kt = s - 3;  K = 128; }
    else if (s < 11) { src = w_ih1; kt = s - 7;  K = 128; }
    else             { src = w_hh1; kt = s - 11; K = 128; }
    int row = g * 128 + w * 16 + (lane & 15);
    int k0  = kt * 32 + (lane >> 4) * 8;
    half8 v;
    #pragma unroll
    for (int j = 0; j < 8; ++j) v[j] = (_Float16)src[row * K + k0 + j];
    pP[tid] = v;
}

__global__ void k_bsum(const float* __restrict__ bi0, const float* __restrict__ bh0,
                       const float* __restrict__ bi1, const float* __restrict__ bh1,
                       float* __restrict__ bs) {
    int i = blockIdx.x * 256 + threadIdx.x;
    if (i < 512)       bs[i] = bi0[i] + bh0[i];
    else if (i < 1024) bs[i] = bi1[i - 512] + bh1[i - 512];
}

// ---------------- fused 2-layer LSTM + FC ----------------
// Weights stream global -> LDS via global_load_lds (round-1 lesson: register
// staging destroys L2/L3 residency of the shared 480 KB weight set).
// Round-2 lesson: the compiler does NOT insert correct waits for LDS-DMA into
// statically-named ring buffers -> NaN. So the wait schedule is hand-placed:
//   - counted `s_waitcnt vmcnt(8)` before each consume (2 newer slots stay in
//     flight; never drain to 0 in the loop)           [T4, counted vmcnt]
//   - raw s_barrier + lgkmcnt(0) only (no vmcnt drain) at the two phase
//     boundaries, so weight DMAs live across barriers [T3 pipeline]

__device__ __forceinline__ void async_copy16(const void* g, void* l) {
    __builtin_amdgcn_global_load_lds(
        (const __attribute__((address_space(1))) unsigned int*)g,
        (__attribute__((address_space(3))) unsigned int*)l, 16, 0, 0);
}

// DMA one 4-KB slot (4 gate-frags) from this wave's contiguous stream into LDS
__device__ __forceinline__ void dma_slot(const char* __restrict__ src, int lane, _Float16* slot) {
    #pragma unroll
    for (int g = 0; g < 4; ++g)
        async_copy16((const void*)(src + g * 1024 + lane * 16), (void*)(slot + g * 512));
}

// wait until this slot's 4 DMA loads have landed: everything issued after it is
// at most 2 slots (8 loads); pf loads only ADD to the outstanding count, which
// makes vmcnt(8) stricter, never laxer. "memory" clobber pins the following
// ds_reads below the wait.
#define VMWAIT8() asm volatile("s_waitcnt vmcnt(8)" ::: "memory")

// barrier WITHOUT vmcnt drain: lgkmcnt(0) publishes our ds_writes, raw
// s_barrier syncs, trailing clobber stops later ds_reads hoisting above.
#define BARRIER_NOVM() do {                                   \
    asm volatile("s_waitcnt lgkmcnt(0)" ::: "memory");        \
    __builtin_amdgcn_s_barrier();                             \
    asm volatile("" ::: "memory");                            \
} while (0)

// consume one k-tile slot: 4 B ds_reads + 3 A ds_reads + 12 MFMAs
__device__ __forceinline__ void mfma_kt(floatx4 acc[4][MT], const _Float16* slot, int lane,
                                        const _Float16* A, int strideA, int koff,
                                        int l15, int quad) {
    half8 bg[4], a[MT];
    #pragma unroll
    for (int g = 0; g < 4; ++g) bg[g] = *(const half8*)(slot + g * 512 + lane * 8);
    #pragma unroll
    for (int mt = 0; mt < MT; ++mt)
        a[mt] = *(const half8*)(A + (mt * 16 + l15) * strideA + koff + quad * 8);
    #pragma unroll
    for (int g = 0; g < 4; ++g)
        #pragma unroll
        for (int mt = 0; mt < MT; ++mt)
            acc[g][mt] = __builtin_amdgcn_mfma_f32_16x16x32_f16(a[mt], bg[g], acc[g][mt], 0, 0, 0);
}

__device__ __forceinline__ void epilogue(floatx4 acc[4][MT],
                                         float c[MT][4], _Float16* Hnext,
                                         int quad, int ch) {
    #pragma unroll
    for (int mt = 0; mt < MT; ++mt) {
        #pragma unroll
        for (int r = 0; r < 4; ++r) {
            float gi = acc[0][mt][r];
            float gf = acc[1][mt][r];
            float gg = acc[2][mt][r];
            float go = acc[3][mt][r];
            float cn = sigm_f(gf) * c[mt][r] + sigm_f(gi) * tanh_f(gg);
            c[mt][r] = cn;
            float h = sigm_f(go) * tanh_f(cn);
            Hnext[(mt * 16 + quad * 4 + r) * H_STRIDE + ch] = (_Float16)h;
        }
    }
}

__global__ __launch_bounds__(512, 2) void k_lstm(
    const float* __restrict__ seq, const float* __restrict__ gcn,
    const char* __restrict__ pW, const float* __restrict__ bsum,
    const float* __restrict__ fcw, const float* __restrict__ fcb,
    float* __restrict__ out) {

    __shared__ __align__(16) _Float16 sSeq[48 * SEQ_STRIDE];          //  9,984 B
    __shared__ __align__(16) _Float16 sH0[2][48 * H_STRIDE];          // 26,112 B
    __shared__ __align__(16) _Float16 sH1[2][48 * H_STRIDE];          // 26,112 B
    __shared__ __align__(16) _Float16 sWa[8][2048];                   // 32,768 B
    __shared__ __align__(16) _Float16 sWb[8][2048];                   // 32,768 B
    __shared__ __align__(16) _Float16 sWc[8][2048];                   // 32,768 B
                                                                      // total 160,512 B

    const int tid  = threadIdx.x;
    const int wid  = tid >> 6;
    const int lane = tid & 63;
    const int l15  = lane & 15;
    const int quad = lane >> 4;
    const int node0 = blockIdx.x * M_BLK;
    const int ch = wid * 16 + l15;

    const char* pWw = pW + wid * WAVE_STREAM;   // this wave's contiguous weight stream

#define DMA(S, RING)                  dma_slot(pWw + (S) * 4096, lane, &RING[wid][0])
#define USE(RING, Aptr, stride, koff) mfma_kt(acc, &RING[wid][0], lane, (Aptr), (stride), (koff), l15, quad)

    // prologue DMA: slots 0,1 in flight during setup (ring a, b)
    DMA(0, sWa);
    DMA(1, sWb);

    // zero LDS A-buffers (pad rows 40..47 stay zero forever)
    for (int i = tid; i < 48 * SEQ_STRIDE; i += 512) sSeq[i] = (_Float16)0.f;
    for (int i = tid; i < 48 * H_STRIDE; i += 512) {
        sH0[0][i] = (_Float16)0.f; sH0[1][i] = (_Float16)0.f;
        sH1[0][i] = (_Float16)0.f; sH1[1][i] = (_Float16)0.f;
    }

    float bias0[4], bias1[4];
    #pragma unroll
    for (int g = 0; g < 4; ++g) {
        bias0[g] = bsum[g * 128 + ch];
        bias1[g] = bsum[512 + g * 128 + ch];
    }

    float c0[MT][4] = {{0}}, c1[MT][4] = {{0}};

    __syncthreads();   // setup barrier (full drain once is fine)

    // stage constant gcn columns (32..95) and seq t=0 (cols 0..31)
    for (int i = tid; i < M_BLK * (C_GCN / 2); i += 512) {
        int r = i >> 5, cp = (i & 31) * 2;
        floatx2 v = *(const floatx2*)(gcn + (size_t)(node0 + r) * C_GCN + cp);
        sSeq[r * SEQ_STRIDE + S_SEQ + cp]     = (_Float16)v.x;
        sSeq[r * SEQ_STRIDE + S_SEQ + cp + 1] = (_Float16)v.y;
    }
    {
        int r = tid >> 4, cp = (tid & 15) * 2;
        if (tid < M_BLK * 16) {
            floatx2 v = *(const floatx2*)(seq + ((size_t)(node0 + r) * T_SEQ) * S_SEQ + cp);
            sSeq[r * SEQ_STRIDE + cp]     = (_Float16)v.x;
            sSeq[r * SEQ_STRIDE + cp + 1] = (_Float16)v.y;
        }
    }
    __syncthreads();   // setup barrier

    floatx4 acc[4][MT];
    const int pr = tid >> 4, pc = (tid & 15) * 2;   // seq prefetch slot

    for (int t = 0; t < T_SEQ; ++t) {
        const int cur = t & 1, nxt = cur ^ 1;
        const _Float16* h0c = &sH0[cur][0];
        _Float16*       h0n = &sH0[nxt][0];
        const _Float16* h1c = &sH1[cur][0];
        _Float16*       h1n = &sH1[nxt][0];

        // register prefetch of seq(t+1): in flight through phase A
        floatx2 pf0 = {0.f, 0.f}, pf1 = {0.f, 0.f};
        if (t + 1 < T_SEQ) {
            pf0 = *(const floatx2*)(seq + ((size_t)(node0 + pr) * T_SEQ + (t + 1)) * S_SEQ + pc);
            if (tid < 128) {
                int r1 = (512 + tid) >> 4, c1r = ((512 + tid) & 15) * 2;
                pf1 = *(const floatx2*)(seq + ((size_t)(node0 + r1) * T_SEQ + (t + 1)) * S_SEQ + c1r);
            }
        }

        // ---- phase A: slots 0..6 (0..2: sSeq x IH0, 3..6: sH0 x HH0) ----
        #pragma unroll
        for (int g = 0; g < 4; ++g) {
            floatx4 bv = {bias0[g], bias0[g], bias0[g], bias0[g]};
            #pragma unroll
            for (int mt = 0; mt < MT; ++mt) acc[g][mt] = bv;
        }
        DMA(2, sWc);  VMWAIT8();  USE(sWa, sSeq, SEQ_STRIDE, 0);    // slot 0
        DMA(3, sWa);  VMWAIT8();  USE(sWb, sSeq, SEQ_STRIDE, 32);   // slot 1
        DMA(4, sWb);  VMWAIT8();  USE(sWc, sSeq, SEQ_STRIDE, 64);   // slot 2
        DMA(5, sWc);  VMWAIT8();  USE(sWa, h0c, H_STRIDE, 0);       // slot 3
        DMA(6, sWa);  VMWAIT8();  USE(sWb, h0c, H_STRIDE, 32);      // slot 4
        DMA(7, sWb);  VMWAIT8();  USE(sWc, h0c, H_STRIDE, 64);      // slot 5
        DMA(8, sWc);  VMWAIT8();  USE(sWa, h0c, H_STRIDE, 96);      // slot 6
        epilogue(acc, c0, h0n, quad, ch);
        BARRIER_NOVM();   // h0(t) visible for layer 1; weight DMAs stay in flight

        // ---- phase B: slots 7..14 (7..10: sH0[nxt] x IH1, 11..14: sH1 x HH1) ----
        #pragma unroll
        for (int g = 0; g < 4; ++g) {
            floatx4 bv = {bias1[g], bias1[g], bias1[g], bias1[g]};
            #pragma unroll
            for (int mt = 0; mt < MT; ++mt) acc[g][mt] = bv;
        }
        DMA(9,  sWa); VMWAIT8();  USE(sWb, h0n, H_STRIDE, 0);       // slot 7
        DMA(10, sWb); VMWAIT8();  USE(sWc, h0n, H_STRIDE, 32);      // slot 8
        DMA(11, sWc); VMWAIT8();  USE(sWa, h0n, H_STRIDE, 64);      // slot 9
        DMA(12, sWa); VMWAIT8();  USE(sWb, h0n, H_STRIDE, 96);      // slot 10
        DMA(13, sWb); VMWAIT8();  USE(sWc, h1c, H_STRIDE, 0);       // slot 11
        DMA(14, sWc); VMWAIT8();  USE(sWa, h1c, H_STRIDE, 32);      // slot 12
        DMA(0,  sWa); VMWAIT8();  USE(sWb, h1c, H_STRIDE, 64);      // slot 13: prefetch next-step slot 0
        DMA(1,  sWb); VMWAIT8();  USE(sWc, h1c, H_STRIDE, 96);      // slot 14: prefetch next-step slot 1

        // commit seq(t+1) from prefetch regs (phase-A readers of sSeq are done)
        if (t + 1 < T_SEQ) {
            sSeq[pr * SEQ_STRIDE + pc]     = (_Float16)pf0.x;
            sSeq[pr * SEQ_STRIDE + pc + 1] = (_Float16)pf0.y;
            if (tid < 128) {
                int r1 = (512 + tid) >> 4, c1r = ((512 + tid) & 15) * 2;
                sSeq[r1 * SEQ_STRIDE + c1r]     = (_Float16)pf1.x;
                sSeq[r1 * SEQ_STRIDE + c1r + 1] = (_Float16)pf1.y;
            }
        }
        epilogue(acc, c1, h1n, quad, ch);
        BARRIER_NOVM();   // h1(t) + seq(t+1) visible
    }

#undef DMA
#undef USE

    // drain the tail DMAs (slots 0/1 prefetched for the nonexistent step 96)
    // before LDS deallocation at endpgm
    asm volatile("s_waitcnt vmcnt(0)" ::: "memory");

    // final h1 lives in buffer (T_SEQ & 1) == 0
    if (tid < M_BLK) {
        const _Float16* h1 = &sH1[0][tid * H_STRIDE];
        float s = fcb[0];
        #pragma unroll 16
        for (int k = 0; k < HID; ++k) s = fmaf((float)h1[k], fcw[k], s);
        out[node0 + tid] = s;
    }
}

// ---------------- launch ----------------
extern "C" void kernel_launch(void* const* d_in, const int* in_sizes, int n_in,
                              void* d_out, int out_size, void* d_ws, size_t ws_size,
                              hipStream_t stream) {
    const float* seq   = (const float*)d_in[0];
    const int*   ei    = (const int*)d_in[1];     // int64 in reference -> int32 on device
    // d_in[2] edge_attr: unused by reference
    const float* nf    = (const float*)d_in[3];
    // d_in[4] node_indices: unused by reference
    const float* gcn_w = (const float*)d_in[5];
    const float* gcn_b = (const float*)d_in[6];
    const float* w_ih0 = (const float*)d_in[7];
    const float* w_hh0 = (const float*)d_in[8];
    const float* b_ih0 = (const float*)d_in[9];
    const float* b_hh0 = (const float*)d_in[10];
    const float* w_ih1 = (const float*)d_in[11];
    const float* w_hh1 = (const float*)d_in[12];
    const float* b_ih1 = (const float*)d_in[13];
    const float* b_hh1 = (const float*)d_in[14];
    const float* fc_w  = (const float*)d_in[15];
    const float* fc_b  = (const float*)d_in[16];
    float* out = (float*)d_out;

    char* ws = (char*)d_ws;
    float* xw   = (float*)(ws);                    // 2,560,000 B
    float* gout = (float*)(ws + 2621440);          // 2,560,000 B
    float* deg  = (float*)(ws + 5242880);          // 40,000 B
    float* dinv = (float*)(ws + 5283840);          // 40,000 B
    float* bsum = (float*)(ws + 5324800);          // 4,096 B
    char*  pP   = (char*)(ws + 5328896);           // 491,520 B (16B aligned)

    // GCN (fp32 exact)
    k_gcn_xw     <<<2500,  256, 0, stream>>>(nf, gcn_w, xw);
    k_deg_init   <<<40,    256, 0, stream>>>(deg);
    k_deg_count  <<<625,   256, 0, stream>>>(ei, deg);
    k_dinv       <<<40,    256, 0, stream>>>(deg, dinv);
    k_gcn_self   <<<2500,  256, 0, stream>>>(xw, dinv, gcn_b, gout);
    k_gcn_scatter<<<40000, 256, 0, stream>>>(ei, xw, dinv, gout);

    // weight prep (wave-major streaming layout)
    k_pack<<<120, 256, 0, stream>>>(w_ih0, w_hh0, w_ih1, w_hh1, (half8*)pP);
    k_bsum<<<4,   256, 0, stream>>>(b_ih0, b_hh0, b_ih1, b_hh1, bsum);

    // fused 2-layer LSTM + FC
    k_lstm<<<250, 512, 0, stream>>>(seq, gout, pP, bsum, fc_w, fc_b, out);
}